// Round 13
// baseline (24.505 us; speedup 1.0000x reference)
//
#include <hip/hip_runtime.h>
#include <math.h>

#define Bq 4
#define Kq 16
#define Nq 2048
#define Dq 256

typedef float f32x4 __attribute__((ext_vector_type(4)));
typedef short s16x8 __attribute__((ext_vector_type(8)));
typedef unsigned int u32;

union frag_u { s16x8 v; u32 w[4]; };

// ws layout (floats):
//   [0    .. 1024)  : S1  lane layout [b][lane] (f32x4)
//   [1024 .. 2048)  : G_I lane layout [b][lane] (f32x4)
//   [2048 .. 10240) : logits (4 x 2048)

static __device__ __forceinline__ u32 cvtpk(float a, float b) {
    u32 r;
    asm("v_cvt_pk_bf16_f32 %0, %1, %2" : "=v"(r) : "v"(a), "v"(b));
    return r;
}

static __device__ __forceinline__ void cvt2(float a, float b, u32* hw, u32* lw) {
    const u32 h = cvtpk(a, b);
    const float h0 = __uint_as_float(h << 16);
    const float h1 = __uint_as_float(h & 0xFFFF0000u);
    *hw = h;
    *lw = cvtpk(a - h0, b - h1);
}

static __device__ __forceinline__ void conv8(const f32x4 a, const f32x4 b,
                                             s16x8* hi, s16x8* lo) {
    frag_u H, L;
    cvt2(a[0], a[1], &H.w[0], &L.w[0]);
    cvt2(a[2], a[3], &H.w[1], &L.w[1]);
    cvt2(b[0], b[1], &H.w[2], &L.w[2]);
    cvt2(b[2], b[3], &H.w[3], &L.w[3]);
    *hi = H.v; *lo = L.v;
}

static __device__ __forceinline__ float rdlane(float x, int l) {
    return __uint_as_float((u32)__builtin_amdgcn_readlane((int)__float_as_uint(x), l));
}

#define MFMA(A, B, C) __builtin_amdgcn_mfma_f32_16x16x32_bf16((A), (B), (C), 0, 0, 0)

// partial Gram over one 64-wide K slice (4 f32x4 per lane = 2 MFMA k-windows)
static __device__ __forceinline__ f32x4 gram2(const f32x4* x, f32x4 g) {
    s16x8 hi, lo;
    conv8(x[0], x[1], &hi, &lo);
    g = MFMA(hi, hi, g); g = MFMA(hi, lo, g); g = MFMA(lo, hi, g);
    conv8(x[2], x[3], &hi, &lo);
    g = MFMA(hi, hi, g); g = MFMA(hi, lo, g); g = MFMA(lo, hi, g);
    return g;
}

// (G + lam I) M = (rho-1) G - lam I solved per-wave: lane j (mod 16) owns
// column j; pivot broadcast via v_readlane (static index, fully unrolled).
// Returns S = M*M in MFMA C/D lane layout. scr = per-wave [16][20] LDS.
static __device__ __forceinline__ f32x4 solve_S(f32x4 g, float lam, float rho,
                                                float (*scr)[20], int lane) {
    const int ccol = lane & 15, kgrp = lane >> 4, arow = ccol, j = ccol;
    *reinterpret_cast<f32x4*>(&scr[ccol][kgrp * 4]) = g;
    __builtin_amdgcn_wave_barrier();
    float A[16], rhs[16];
    {
        const float* col = &scr[j][0];
        const f32x4 c0 = *reinterpret_cast<const f32x4*>(col + 0);
        const f32x4 c1 = *reinterpret_cast<const f32x4*>(col + 4);
        const f32x4 c2 = *reinterpret_cast<const f32x4*>(col + 8);
        const f32x4 c3 = *reinterpret_cast<const f32x4*>(col + 12);
        float gv[16];
#pragma unroll
        for (int q = 0; q < 4; ++q) {
            gv[q] = c0[q]; gv[4 + q] = c1[q]; gv[8 + q] = c2[q]; gv[12 + q] = c3[q];
        }
#pragma unroll
        for (int i = 0; i < 16; ++i) {
            const float dv = (i == j) ? lam : 0.f;
            A[i]   = gv[i] + dv;
            rhs[i] = (rho - 1.f) * gv[i] - dv;
        }
    }
    __builtin_amdgcn_wave_barrier();

#pragma unroll
    for (int k = 0; k < Kq; ++k) {
        const float pinv = 1.0f / rdlane(A[k], k);
        A[k]   *= pinv;
        rhs[k] *= pinv;
#pragma unroll
        for (int i = 0; i < 16; ++i) {
            if (i == k) continue;
            const float fac = rdlane(A[i], k);
            A[i]   = fmaf(-fac, A[k],   A[i]);
            rhs[i] = fmaf(-fac, rhs[k], rhs[i]);
        }
    }
#pragma unroll
    for (int i = 0; i < 16; ++i) scr[i][j] = rhs[i];
    __builtin_amdgcn_wave_barrier();

    frag_u H, L;
#pragma unroll
    for (int e = 0; e < 8; e += 2) {
        const int kk = (kgrp & 1) * 8 + e;
        const bool vld = (lane < 32);
        const float m0 = vld ? scr[arow][kk]     : 0.f;
        const float m1 = vld ? scr[arow][kk + 1] : 0.f;
        cvt2(m0, m1, &H.w[e >> 1], &L.w[e >> 1]);
    }
    f32x4 s = {0.f, 0.f, 0.f, 0.f};
    s = MFMA(H.v, H.v, s); s = MFMA(H.v, L.v, s); s = MFMA(L.v, H.v, s);
    return s;
}

// Kernel A (R12-verified): 4 blocks x 256 threads, cooperative img solve.
__global__ __launch_bounds__(256) void img_kernel(const float* __restrict__ img,
                                                  const float* __restrict__ r,
                                                  float* __restrict__ ws) {
    __shared__ __align__(16) f32x4 shG[4][64];
    __shared__ __align__(16) float scr[16][20];
    const int tid  = threadIdx.x;
    const int w    = tid >> 6, lane = tid & 63;
    const int arow = lane & 15, kgrp = lane >> 4;
    const int b    = blockIdx.x;

    const float* base = img + b * (Kq * Dq) + arow * Dq + kgrp * 8;
    f32x4 x[4];
    x[0] = *reinterpret_cast<const f32x4*>(base + (2 * w) * 32);
    x[1] = *reinterpret_cast<const f32x4*>(base + (2 * w) * 32 + 4);
    x[2] = *reinterpret_cast<const f32x4*>(base + (2 * w + 1) * 32);
    x[3] = *reinterpret_cast<const f32x4*>(base + (2 * w + 1) * 32 + 4);

    f32x4 g = {0.f, 0.f, 0.f, 0.f};
    shG[w][lane] = gram2(x, g);
    __syncthreads();
    if (w != 0) return;

    const f32x4 gI = shG[0][lane] + shG[1][lane] + shG[2][lane] + shG[3][lane];
    const float lam = (float(Bq) / float(Dq)) * expf(r[0]) + 1e-6f;
    const float rho = expf(r[1]);
    const f32x4 s = solve_S(gI, lam, rho, scr, lane);
    reinterpret_cast<f32x4*>(ws)[b * 64 + lane]        = s;
    reinterpret_cast<f32x4*>(ws + 1024)[b * 64 + lane] = gI;
}

// Kernel B: 1024 blocks x 256 threads, TWO texts per block.
// Wave w grams K-half (w>>1) of text 2*blk + (w&1); waves 0 AND 1 solve the
// two texts in parallel (halved serial tail vs 1-solver-wave). S1/GI loads
// are hoisted before the solve so their L2 latency hides under the GJ.
__global__ __launch_bounds__(256) void text_kernel(const float* __restrict__ text,
                                                   const float* __restrict__ r,
                                                   const float* __restrict__ alp,
                                                   const float* __restrict__ scale,
                                                   float* __restrict__ ws) {
    __shared__ __align__(16) f32x4 shG[4][64];
    __shared__ __align__(16) float scr[2][16][20];
    const int tid  = threadIdx.x;
    const int w    = tid >> 6, lane = tid & 63;
    const int arow = lane & 15, kgrp = lane >> 4;
    const int tsel  = w & 1;    // which of the two texts
    const int khalf = w >> 1;   // which 128-wide K half
    const int n     = blockIdx.x * 2 + tsel;

    // two 64-wide slices (chunks 4*khalf .. 4*khalf+3)
    const float* base = text + n * (Kq * Dq) + arow * Dq + kgrp * 8 + khalf * 128;
    f32x4 x[8];
#pragma unroll
    for (int c = 0; c < 4; ++c) {
        x[2 * c]     = *reinterpret_cast<const f32x4*>(base + c * 32);
        x[2 * c + 1] = *reinterpret_cast<const f32x4*>(base + c * 32 + 4);
    }
    f32x4 g = {0.f, 0.f, 0.f, 0.f};
    g = gram2(x, g);
    g = gram2(x + 4, g);
    shG[w][lane] = g;
    __syncthreads();
    if (w >= 2) return;   // waves 2,3 done (all reached the barrier)

    // wave 0 -> text 2*blk (shG[0]+shG[2]); wave 1 -> text 2*blk+1 (shG[1]+shG[3])
    const f32x4 gT = shG[tsel][lane] + shG[tsel + 2][lane];

    // hoist S1/GI loads: L2 latency hides under the register GJ below
    f32x4 s1v[4], giv[4];
#pragma unroll
    for (int b = 0; b < 4; ++b) {
        s1v[b] = reinterpret_cast<const f32x4*>(ws)[b * 64 + lane];
        giv[b] = reinterpret_cast<const f32x4*>(ws + 1024)[b * 64 + lane];
    }

    const float lamT = (float(Nq) / float(Dq)) * expf(r[2]) + 1e-6f;
    const float rhoT = expf(r[3]);
    const f32x4 sT = solve_S(gT, lamT, rhoT, scr[w], lane);

    float p[8];
#pragma unroll
    for (int b = 0; b < 4; ++b) {
        p[b]     = s1v[b][0] * gT[0] + s1v[b][1] * gT[1] + s1v[b][2] * gT[2] + s1v[b][3] * gT[3];
        p[4 + b] = giv[b][0] * sT[0] + giv[b][1] * sT[1] + giv[b][2] * sT[2] + giv[b][3] * sT[3];
    }
#pragma unroll
    for (int off = 32; off; off >>= 1) {
#pragma unroll
        for (int q = 0; q < 8; ++q) p[q] += __shfl_down(p[q], off, 64);
    }
    if (lane == 0) {
        const float a = alp[0], sc = scale[0];
        float* logits = ws + 2048;
#pragma unroll
        for (int b = 0; b < 4; ++b) {
            const float d1 = -p[b] * (1.f / Kq);
            const float d2 = -p[4 + b] * (1.f / Kq);
            logits[b * Nq + n] = sc * (a * d1 + (1.f - a) * d2);
        }
    }
}

__global__ __launch_bounds__(256) void softmax_kernel(const float* __restrict__ logits,
                                                      const float* __restrict__ lsc,
                                                      float* __restrict__ out) {
    const int b   = blockIdx.x;
    const int tid = threadIdx.x;
    const float* row = logits + b * Nq;
    __shared__ float sh[4];
    float v[8];
    float mx = -INFINITY;
#pragma unroll
    for (int q = 0; q < 8; ++q) {
        v[q] = row[tid + q * 256];
        mx = fmaxf(mx, v[q]);
    }
#pragma unroll
    for (int off = 32; off; off >>= 1) mx = fmaxf(mx, __shfl_down(mx, off, 64));
    if ((tid & 63) == 0) sh[tid >> 6] = mx;
    __syncthreads();
    mx = fmaxf(fmaxf(sh[0], sh[1]), fmaxf(sh[2], sh[3]));

    float sum = 0.f;
#pragma unroll
    for (int q = 0; q < 8; ++q) sum += expf(v[q] - mx);
#pragma unroll
    for (int off = 32; off; off >>= 1) sum += __shfl_down(sum, off, 64);
    __syncthreads();
    if ((tid & 63) == 0) sh[tid >> 6] = sum;
    __syncthreads();
    sum = sh[0] + sh[1] + sh[2] + sh[3];

    const float lse = mx + logf(sum);
#pragma unroll
    for (int q = 0; q < 8; ++q) out[b * Nq + tid + q * 256] = v[q] - lse;
    if (b == 0 && tid == 0) out[Bq * Nq] = 1.f / (1.f + expf(-lsc[0]));
}

extern "C" void kernel_launch(void* const* d_in, const int* in_sizes, int n_in,
                              void* d_out, int out_size, void* d_ws, size_t ws_size,
                              hipStream_t stream) {
    const float* img   = (const float*)d_in[0];
    const float* text  = (const float*)d_in[1];
    const float* r     = (const float*)d_in[2];
    const float* alp   = (const float*)d_in[3];
    const float* scale = (const float*)d_in[4];
    const float* lsc   = (const float*)d_in[5];
    float* ws  = (float*)d_ws;
    float* out = (float*)d_out;

    img_kernel<<<Bq, 256, 0, stream>>>(img, r, ws);
    text_kernel<<<Nq / 2, 256, 0, stream>>>(text, r, alp, scale, ws);
    softmax_kernel<<<Bq, 256, 0, stream>>>(ws + 2048, lsc, out);
}

// Round 14
// 22.574 us; speedup vs baseline: 1.0855x; 1.0855x over previous
//
#include <hip/hip_runtime.h>
#include <math.h>

#define Bq 4
#define Kq 16
#define Nq 2048
#define Dq 256

typedef float f32x4 __attribute__((ext_vector_type(4)));
typedef short s16x8 __attribute__((ext_vector_type(8)));
typedef unsigned int u32;

union frag_u { s16x8 v; u32 w[4]; };

// ws layout (floats):
//   [0    .. 1024)  : S1  lane layout [b][lane] (f32x4)
//   [1024 .. 2048)  : G_I lane layout [b][lane] (f32x4)
//   [2048 .. 10240) : logits (4 x 2048)

static __device__ __forceinline__ u32 cvtpk(float a, float b) {
    u32 r;
    asm("v_cvt_pk_bf16_f32 %0, %1, %2" : "=v"(r) : "v"(a), "v"(b));
    return r;
}

static __device__ __forceinline__ void cvt2(float a, float b, u32* hw, u32* lw) {
    const u32 h = cvtpk(a, b);
    const float h0 = __uint_as_float(h << 16);
    const float h1 = __uint_as_float(h & 0xFFFF0000u);
    *hw = h;
    *lw = cvtpk(a - h0, b - h1);
}

static __device__ __forceinline__ void conv8(const f32x4 a, const f32x4 b,
                                             s16x8* hi, s16x8* lo) {
    frag_u H, L;
    cvt2(a[0], a[1], &H.w[0], &L.w[0]);
    cvt2(a[2], a[3], &H.w[1], &L.w[1]);
    cvt2(b[0], b[1], &H.w[2], &L.w[2]);
    cvt2(b[2], b[3], &H.w[3], &L.w[3]);
    *hi = H.v; *lo = L.v;
}

static __device__ __forceinline__ float rdlane(float x, int l) {
    return __uint_as_float((u32)__builtin_amdgcn_readlane((int)__float_as_uint(x), l));
}

#define MFMA(A, B, C) __builtin_amdgcn_mfma_f32_16x16x32_bf16((A), (B), (C), 0, 0, 0)

// partial Gram over one 64-wide K slice (4 f32x4 per lane = 2 MFMA k-windows)
static __device__ __forceinline__ f32x4 gram2(const f32x4* x, f32x4 g) {
    s16x8 hi, lo;
    conv8(x[0], x[1], &hi, &lo);
    g = MFMA(hi, hi, g); g = MFMA(hi, lo, g); g = MFMA(lo, hi, g);
    conv8(x[2], x[3], &hi, &lo);
    g = MFMA(hi, hi, g); g = MFMA(hi, lo, g); g = MFMA(lo, hi, g);
    return g;
}

// (G + lam I) M = (rho-1) G - lam I solved per-wave: lane j (mod 16) owns
// column j; pivot broadcast via v_readlane (static index, fully unrolled).
// Returns S = M*M in MFMA C/D lane layout. scr = per-block [16][20] LDS.
static __device__ __forceinline__ f32x4 solve_S(f32x4 g, float lam, float rho,
                                                float (*scr)[20], int lane) {
    const int ccol = lane & 15, kgrp = lane >> 4, arow = ccol, j = ccol;
    *reinterpret_cast<f32x4*>(&scr[ccol][kgrp * 4]) = g;
    __builtin_amdgcn_wave_barrier();
    float A[16], rhs[16];
    {
        const float* col = &scr[j][0];
        const f32x4 c0 = *reinterpret_cast<const f32x4*>(col + 0);
        const f32x4 c1 = *reinterpret_cast<const f32x4*>(col + 4);
        const f32x4 c2 = *reinterpret_cast<const f32x4*>(col + 8);
        const f32x4 c3 = *reinterpret_cast<const f32x4*>(col + 12);
        float gv[16];
#pragma unroll
        for (int q = 0; q < 4; ++q) {
            gv[q] = c0[q]; gv[4 + q] = c1[q]; gv[8 + q] = c2[q]; gv[12 + q] = c3[q];
        }
#pragma unroll
        for (int i = 0; i < 16; ++i) {
            const float dv = (i == j) ? lam : 0.f;
            A[i]   = gv[i] + dv;
            rhs[i] = (rho - 1.f) * gv[i] - dv;
        }
    }
    __builtin_amdgcn_wave_barrier();

#pragma unroll
    for (int k = 0; k < Kq; ++k) {
        const float pinv = 1.0f / rdlane(A[k], k);
        A[k]   *= pinv;
        rhs[k] *= pinv;
#pragma unroll
        for (int i = 0; i < 16; ++i) {
            if (i == k) continue;
            const float fac = rdlane(A[i], k);
            A[i]   = fmaf(-fac, A[k],   A[i]);
            rhs[i] = fmaf(-fac, rhs[k], rhs[i]);
        }
    }
#pragma unroll
    for (int i = 0; i < 16; ++i) scr[i][j] = rhs[i];
    __builtin_amdgcn_wave_barrier();

    frag_u H, L;
#pragma unroll
    for (int e = 0; e < 8; e += 2) {
        const int kk = (kgrp & 1) * 8 + e;
        const bool vld = (lane < 32);
        const float m0 = vld ? scr[arow][kk]     : 0.f;
        const float m1 = vld ? scr[arow][kk + 1] : 0.f;
        cvt2(m0, m1, &H.w[e >> 1], &L.w[e >> 1]);
    }
    f32x4 s = {0.f, 0.f, 0.f, 0.f};
    s = MFMA(H.v, H.v, s); s = MFMA(H.v, L.v, s); s = MFMA(L.v, H.v, s);
    return s;
}

// Kernel A: 4 blocks x 256 threads (cooperative): wave w grams K-slice w of
// img matrix b = blockIdx.x; wave 0 reduces + solves.
__global__ __launch_bounds__(256) void img_kernel(const float* __restrict__ img,
                                                  const float* __restrict__ r,
                                                  float* __restrict__ ws) {
    __shared__ __align__(16) f32x4 shG[4][64];
    __shared__ __align__(16) float scr[16][20];
    const int tid  = threadIdx.x;
    const int w    = tid >> 6, lane = tid & 63;
    const int arow = lane & 15, kgrp = lane >> 4;
    const int b    = blockIdx.x;

    const float* base = img + b * (Kq * Dq) + arow * Dq + kgrp * 8;
    f32x4 x[4];
    x[0] = *reinterpret_cast<const f32x4*>(base + (2 * w) * 32);
    x[1] = *reinterpret_cast<const f32x4*>(base + (2 * w) * 32 + 4);
    x[2] = *reinterpret_cast<const f32x4*>(base + (2 * w + 1) * 32);
    x[3] = *reinterpret_cast<const f32x4*>(base + (2 * w + 1) * 32 + 4);

    f32x4 g = {0.f, 0.f, 0.f, 0.f};
    shG[w][lane] = gram2(x, g);
    __syncthreads();
    if (w != 0) return;

    const f32x4 gI = shG[0][lane] + shG[1][lane] + shG[2][lane] + shG[3][lane];
    const float lam = (float(Bq) / float(Dq)) * expf(r[0]) + 1e-6f;
    const float rho = expf(r[1]);
    const f32x4 s = solve_S(gI, lam, rho, scr, lane);
    reinterpret_cast<f32x4*>(ws)[b * 64 + lane]        = s;
    reinterpret_cast<f32x4*>(ws + 1024)[b * 64 + lane] = gI;
}

// Kernel B: 2048 blocks x 256 threads, ONE text per block (all co-resident).
// Wave w: partial Gram over K-slice w; wave 0 reduces + solves (register GJ)
// and writes the 4 logits.
__global__ __launch_bounds__(256) void text_kernel(const float* __restrict__ text,
                                                   const float* __restrict__ r,
                                                   const float* __restrict__ alp,
                                                   const float* __restrict__ scale,
                                                   float* __restrict__ ws) {
    __shared__ __align__(16) f32x4 shG[4][64];
    __shared__ __align__(16) float scr[16][20];
    const int tid  = threadIdx.x;
    const int w    = tid >> 6, lane = tid & 63;
    const int arow = lane & 15, kgrp = lane >> 4;
    const int n    = blockIdx.x;

    const float* base = text + n * (Kq * Dq) + arow * Dq + kgrp * 8;
    f32x4 x[4];
    x[0] = *reinterpret_cast<const f32x4*>(base + (2 * w) * 32);
    x[1] = *reinterpret_cast<const f32x4*>(base + (2 * w) * 32 + 4);
    x[2] = *reinterpret_cast<const f32x4*>(base + (2 * w + 1) * 32);
    x[3] = *reinterpret_cast<const f32x4*>(base + (2 * w + 1) * 32 + 4);

    f32x4 g = {0.f, 0.f, 0.f, 0.f};
    shG[w][lane] = gram2(x, g);
    __syncthreads();
    if (w != 0) return;   // waves 1-3 done (all reached the barrier)

    const f32x4 gT = shG[0][lane] + shG[1][lane] + shG[2][lane] + shG[3][lane];
    const float lamT = (float(Nq) / float(Dq)) * expf(r[2]) + 1e-6f;
    const float rhoT = expf(r[3]);
    const f32x4 sT = solve_S(gT, lamT, rhoT, scr, lane);

    // img S1/G_I (8KB, cache-hot): load after the solve
    f32x4 s1v[4], giv[4];
#pragma unroll
    for (int b = 0; b < 4; ++b) {
        s1v[b] = reinterpret_cast<const f32x4*>(ws)[b * 64 + lane];
        giv[b] = reinterpret_cast<const f32x4*>(ws + 1024)[b * 64 + lane];
    }
    float p[8];
#pragma unroll
    for (int b = 0; b < 4; ++b) {
        p[b]     = s1v[b][0] * gT[0] + s1v[b][1] * gT[1] + s1v[b][2] * gT[2] + s1v[b][3] * gT[3];
        p[4 + b] = giv[b][0] * sT[0] + giv[b][1] * sT[1] + giv[b][2] * sT[2] + giv[b][3] * sT[3];
    }
#pragma unroll
    for (int off = 32; off; off >>= 1) {
#pragma unroll
        for (int q = 0; q < 8; ++q) p[q] += __shfl_down(p[q], off, 64);
    }
    if (lane == 0) {
        const float a = alp[0], sc = scale[0];
        float* logits = ws + 2048;
#pragma unroll
        for (int b = 0; b < 4; ++b) {
            const float d1 = -p[b] * (1.f / Kq);
            const float d2 = -p[4 + b] * (1.f / Kq);
            logits[b * Nq + n] = sc * (a * d1 + (1.f - a) * d2);
        }
    }
}

__global__ __launch_bounds__(256) void softmax_kernel(const float* __restrict__ logits,
                                                      const float* __restrict__ lsc,
                                                      float* __restrict__ out) {
    const int b   = blockIdx.x;
    const int tid = threadIdx.x;
    const float* row = logits + b * Nq;
    __shared__ float sh[4];
    float v[8];
    float mx = -INFINITY;
#pragma unroll
    for (int q = 0; q < 8; ++q) {
        v[q] = row[tid + q * 256];
        mx = fmaxf(mx, v[q]);
    }
#pragma unroll
    for (int off = 32; off; off >>= 1) mx = fmaxf(mx, __shfl_down(mx, off, 64));
    if ((tid & 63) == 0) sh[tid >> 6] = mx;
    __syncthreads();
    mx = fmaxf(fmaxf(sh[0], sh[1]), fmaxf(sh[2], sh[3]));

    float sum = 0.f;
#pragma unroll
    for (int q = 0; q < 8; ++q) sum += expf(v[q] - mx);
#pragma unroll
    for (int off = 32; off; off >>= 1) sum += __shfl_down(sum, off, 64);
    __syncthreads();
    if ((tid & 63) == 0) sh[tid >> 6] = sum;
    __syncthreads();
    sum = sh[0] + sh[1] + sh[2] + sh[3];

    const float lse = mx + logf(sum);
#pragma unroll
    for (int q = 0; q < 8; ++q) out[b * Nq + tid + q * 256] = v[q] - lse;
    if (b == 0 && tid == 0) out[Bq * Nq] = 1.f / (1.f + expf(-lsc[0]));
}

extern "C" void kernel_launch(void* const* d_in, const int* in_sizes, int n_in,
                              void* d_out, int out_size, void* d_ws, size_t ws_size,
                              hipStream_t stream) {
    const float* img   = (const float*)d_in[0];
    const float* text  = (const float*)d_in[1];
    const float* r     = (const float*)d_in[2];
    const float* alp   = (const float*)d_in[3];
    const float* scale = (const float*)d_in[4];
    const float* lsc   = (const float*)d_in[5];
    float* ws  = (float*)d_ws;
    float* out = (float*)d_out;

    img_kernel<<<Bq, 256, 0, stream>>>(img, r, ws);
    text_kernel<<<Nq, 256, 0, stream>>>(text, r, alp, scale, ws);
    softmax_kernel<<<Bq, 256, 0, stream>>>(ws + 2048, lsc, out);
}